// Round 11
// baseline (68.721 us; speedup 1.0000x reference)
//
#include <hip/hip_runtime.h>
#include <hip/hip_bf16.h>

#define N_ROWS 8192
#define D_DIM  1024           // elements per row
#define ROWB   512            // fp4 row bytes (1024 elems * 0.5B)
#define DELTA  0.1f
#define EPSF   1e-8f

#define BM 256
#define BN 256
#define BKB 128               // K-tile row bytes = 256 fp4 elems
#define NT (ROWB / BKB)       // 4 K-tiles

typedef __attribute__((ext_vector_type(4))) int   i32x4;
typedef __attribute__((ext_vector_type(8))) int   i32x8;
typedef __attribute__((ext_vector_type(4))) float f32x4;

// Software fp4 (e2m1) encode of v*32, RNE-by-midpoints, clamp at 6.
__device__ inline unsigned int fp4_enc(float v) {
    const unsigned int s = (__float_as_uint(v) >> 31) & 1u;
    float m = fminf(fabsf(v) * 32.0f, 6.0f);
    unsigned int c = 0;
    c += (m >= 0.25f); c += (m >= 0.75f); c += (m >= 1.25f); c += (m >= 1.75f);
    c += (m >= 2.5f);  c += (m >= 3.5f);  c += (m >= 5.0f);
    return (s << 3) | c;
}

// One block per row: compute xx, yy, xy; write normalized fp4 rows (x32) + fp32 pos.
__global__ __launch_bounds__(256) void norm_kernel(
    const float* __restrict__ X, const float* __restrict__ Y,
    unsigned short* __restrict__ Xn, unsigned short* __restrict__ Yn,  // [8192][256] u16
    float* __restrict__ pos)
{
    const int row = blockIdx.x;
    const int t = threadIdx.x;            // 256 threads, 4 f32 each = 1024
    const float4 xv = reinterpret_cast<const float4*>(X + (size_t)row * D_DIM)[t];
    const float4 yv = reinterpret_cast<const float4*>(Y + (size_t)row * D_DIM)[t];

    float xx = xv.x*xv.x + xv.y*xv.y + xv.z*xv.z + xv.w*xv.w;
    float yy = yv.x*yv.x + yv.y*yv.y + yv.z*yv.z + yv.w*yv.w;
    float xy = xv.x*yv.x + xv.y*yv.y + xv.z*yv.z + xv.w*yv.w;

    #pragma unroll
    for (int off = 32; off > 0; off >>= 1) {
        xx += __shfl_xor(xx, off);
        yy += __shfl_xor(yy, off);
        xy += __shfl_xor(xy, off);
    }
    __shared__ float red[12];
    const int wid = t >> 6, lane = t & 63;
    if (lane == 0) { red[wid] = xx; red[4 + wid] = yy; red[8 + wid] = xy; }
    __syncthreads();
    xx = red[0] + red[1] + red[2] + red[3];
    yy = red[4] + red[5] + red[6] + red[7];
    xy = red[8] + red[9] + red[10] + red[11];

    const float rnx = 1.0f / fmaxf(sqrtf(xx), EPSF);
    const float rny = 1.0f / fmaxf(sqrtf(yy), EPSF);
    if (t == 0) pos[row] = xy * rnx * rny;

    // 4 fp4 nibbles -> one u16, K ascending low-to-high (identical for X and Y)
    const unsigned int px = fp4_enc(xv.x * rnx) | (fp4_enc(xv.y * rnx) << 4)
                          | (fp4_enc(xv.z * rnx) << 8) | (fp4_enc(xv.w * rnx) << 12);
    const unsigned int py = fp4_enc(yv.x * rny) | (fp4_enc(yv.y * rny) << 4)
                          | (fp4_enc(yv.z * rny) << 8) | (fp4_enc(yv.w * rny) << 12);
    Xn[(size_t)row * 256 + t] = (unsigned short)px;
    Yn[(size_t)row * 256 + t] = (unsigned short)py;
}

#define GLDS16(gptr, lptr) \
    __builtin_amdgcn_global_load_lds((const __attribute__((address_space(1))) void*)(gptr), \
                                     (__attribute__((address_space(3))) void*)(lptr), 16, 0, 0)

// Plain 16B LDS read into low half of an i32x8 (fp4 operand uses 4 regs; the
// upper 4 are don't-care, zeroed once by the compiler and hoisted).
__device__ inline i32x8 ld16(const unsigned char* p) {
    const i32x4 u = *reinterpret_cast<const i32x4*>(p);
    i32x8 r;
    r[0] = u[0]; r[1] = u[1]; r[2] = u[2]; r[3] = u[3];
    r[4] = 0; r[5] = 0; r[6] = 0; r[7] = 0;
    return r;
}

// One 1KB staging unit (8 rows x 128B): lane -> row j*8+(lane>>3), phys chunk
// lane&7. LDS dest linear (gload_lds rule); swizzle pre-applied to the GLOBAL
// source chunk so LDS[row][p] = G[row][p ^ (row&7)]  (proven zero-conflict).
#define STAGE1(dst, gbase, kkb, j) { \
    const unsigned char* g_ = (gbase) + (size_t)((j) * 8 + srow) * ROWB + (kkb) + schunk * 16; \
    GLDS16(g_, (dst) + (j) * 1024); }

// Stage one 256x128B panel (32 KB): 4 units/thread (wave wv takes j = q*8+wv).
#define STAGE_P(dst, gbase, kkb) { \
    STAGE1(dst, gbase, kkb, wv); STAGE1(dst, gbase, kkb, 8 + wv); \
    STAGE1(dst, gbase, kkb, 16 + wv); STAGE1(dst, gbase, kkb, 24 + wv); }

// Fragment reads: constant-offset derefs off per-tile bases -> the compiler
// folds (g*4+mi)*2048 into the ds_read_b128 offset immediate (max 14336 < 64K).
// Derivation: row&7 == lane&7 for every fragment row, so the swizzled chunk
// pc = (ks*4 + (lane>>4)) ^ (lane&7) is row-independent; consecutive fragment
// rows differ by 16*128 = 2048 bytes exactly.
#define LOAD_A_G(g, pa) { _Pragma("unroll") for (int mi = 0; mi < 4; ++mi) \
    af[mi] = ld16((pa) + ((g) * 4 + mi) * 2048); }

#define LOAD_B_ALL(pb) { _Pragma("unroll") for (int nj = 0; nj < 4; ++nj) \
    bf[nj] = ld16((pb) + nj * 2048); }

// 16 mfma_scale; cbsz=4/blgp=4 = fp4 e2m1; unit scales (0x7F = e8m0 1.0)
#define MFMA_H(g) { _Pragma("unroll") for (int mi = 0; mi < 4; ++mi) { \
    _Pragma("unroll") for (int nj = 0; nj < 4; ++nj) { \
        acc[(g)*4+mi][nj] = __builtin_amdgcn_mfma_scale_f32_16x16x128_f8f6f4( \
            af[mi], bf[nj], acc[(g)*4+mi][nj], 4, 4, 0, 0x7F7F7F7F, 0, 0x7F7F7F7F); } } }

#define PRIO1() __builtin_amdgcn_s_setprio(1)
#define PRIO0() __builtin_amdgcn_s_setprio(0)

// epilogue inner loop; DIAG chosen at block level (diagonal only when row0==col0)
#define EPILOOP(DIAG) { \
    _Pragma("unroll") for (int mi = 0; mi < 8; ++mi) { \
        _Pragma("unroll") for (int jj = 0; jj < 4; ++jj) { \
            const int lr = wm * 128 + mi * 16 + (lane >> 4) * 4 + jj; \
            const float basev = DELTA - sPos[lr]; \
            _Pragma("unroll") for (int nj = 0; nj < 4; ++nj) { \
                float h = fmaxf(fmaf(acc[mi][nj][jj], inv, basev), 0.0f); \
                if (DIAG) { \
                    const int lc = wn * 64 + nj * 16 + (lane & 15); \
                    if (lr == lc) h = 0.0f; \
                } \
                if (nj & 1) l1 += h; else l0 += h; \
            } } } }

// S*1024 = (32Xn)*(32Yn)^T 256x256 fp4 tile; BKB=128B (NT=4) counted-vmcnt
// pipeline, prefetch distance 2, in-place restage; constant-offset ds_reads.
__global__ __launch_bounds__(512, 2) void gemm_loss_kernel(
    const unsigned char* __restrict__ A,   // Xn [N][512B] fp4
    const unsigned char* __restrict__ B,   // Yn [N][512B] fp4
    const float* __restrict__ pos,
    float* __restrict__ out)
{
    __shared__ __align__(16) unsigned char sA[2][BM * BKB];  // 64 KB
    __shared__ __align__(16) unsigned char sB[2][BN * BKB];  // 64 KB
    __shared__ float sPos[BM];
    __shared__ float redW[8];

    // XCD-aware swizzle (1024 blocks, 1024 % 8 == 0 -> bijective)
    const int nwg = gridDim.x;
    const int bid = blockIdx.x;
    const int cpx = nwg >> 3;
    const int swz = (bid & 7) * cpx + (bid >> 3);
    const int row0 = (swz >> 5) * BM;   // 32 tiles per dim
    const int col0 = (swz & 31) * BN;

    const int tid = threadIdx.x;
    const int lane = tid & 63;
    const int wv = tid >> 6;         // 8 waves: 2M x 4N
    const int wm = wv >> 2;          // rows [wm*128, +128)
    const int wn = wv & 3;           // cols [wn*64, +64)

    const int srow = lane >> 3;                     // 0..7
    const int schunk = (lane & 7) ^ srow;           // pre-swizzled global chunk
    const unsigned char* Ab = A + (size_t)row0 * ROWB;
    const unsigned char* Bb = B + (size_t)col0 * ROWB;

    // per-thread invariant fragment-read offsets; k-step 1 chunk = pc0 ^ 4
    const int pc0 = (lane >> 4) ^ (lane & 7);
    const int pc1 = pc0 ^ 4;
    const int arow = wm * 16384 + (lane & 15) * 128;
    const int brow = wn * 8192  + (lane & 15) * 128;
    const int aoff0 = arow + pc0 * 16, aoff1 = arow + pc1 * 16;
    const int boff0 = brow + pc0 * 16, boff1 = brow + pc1 * 16;

    f32x4 acc[8][4] = {};
    i32x8 af[4], bf[4];

    // prologue: stage tiles 0 and 1 (16 stage loads/thread in flight)
    STAGE_P(&sA[0][0], Ab, 0);
    STAGE_P(&sB[0][0], Bb, 0);
    STAGE_P(&sA[1][0], Ab, BKB);
    STAGE_P(&sB[1][0], Bb, BKB);

    #pragma unroll
    for (int kt = 0; kt < NT; ++kt) {
        const int c = kt & 1;
        // counted wait: tile kt's 8 loads (oldest) complete; kt+1's stay in flight
        if (kt == NT - 1) { asm volatile("s_waitcnt vmcnt(0)" ::: "memory"); }
        else              { asm volatile("s_waitcnt vmcnt(8)" ::: "memory"); }
        __builtin_amdgcn_s_barrier();
        __builtin_amdgcn_sched_barrier(0);

        const unsigned char* a = &sA[c][0];
        const unsigned char* b = &sB[c][0];
        const unsigned char* pa0 = a + aoff0;
        const unsigned char* pb0 = b + boff0;
        const unsigned char* pa1 = a + aoff1;
        const unsigned char* pb1 = b + boff1;

        // k-step 0
        LOAD_B_ALL(pb0);
        LOAD_A_G(0, pa0);
        PRIO1(); MFMA_H(0); PRIO0();
        LOAD_A_G(1, pa0);
        PRIO1(); MFMA_H(1); PRIO0();

        // k-step 1
        LOAD_B_ALL(pb1);
        LOAD_A_G(0, pa1);
        PRIO1(); MFMA_H(0); PRIO0();
        LOAD_A_G(1, pa1);
        // all 24 reads of this buffer issued; drain + barrier, then restage
        // in place (stage deadline = boundary kt+2, two tiles away)
        asm volatile("s_waitcnt lgkmcnt(0)" ::: "memory");
        __builtin_amdgcn_s_barrier();
        __builtin_amdgcn_sched_barrier(0);
        if (kt + 2 < NT) {
            STAGE_P(&sA[c][0], Ab, (kt + 2) * BKB);
            STAGE_P(&sB[c][0], Bb, (kt + 2) * BKB);
        }
        PRIO1(); MFMA_H(1); PRIO0();
    }

    // pos staged after the K-loop (keeps in-loop vmcnt accounting pure)
    if (tid < BM) sPos[tid] = pos[row0 + tid];
    __syncthreads();

    // epilogue: hinge = max(0, DELTA - pos[i] + S[i][j]); S = acc/1024 (x32 x32)
    const float inv = 1.0f / 1024.0f;
    float l0 = 0.0f, l1 = 0.0f;
    if (row0 == col0) { EPILOOP(1) } else { EPILOOP(0) }
    float local = l0 + l1;
    #pragma unroll
    for (int off = 32; off > 0; off >>= 1) local += __shfl_xor(local, off);
    if (lane == 0) redW[wv] = local;
    __syncthreads();
    if (tid == 0) {
        float s = 0.0f;
        #pragma unroll
        for (int w = 0; w < 8; ++w) s += redW[w];
        atomicAdd(out, s);
    }
}

extern "C" void kernel_launch(void* const* d_in, const int* in_sizes, int n_in,
                              void* d_out, int out_size, void* d_ws, size_t ws_size,
                              hipStream_t stream) {
    const float* X = (const float*)d_in[0];
    const float* Y = (const float*)d_in[1];
    float* out = (float*)d_out;

    unsigned char* Xn = (unsigned char*)d_ws;                        // 4 MB fp4
    unsigned char* Yn = Xn + (size_t)N_ROWS * ROWB;                  // 4 MB fp4
    float* pos = (float*)(Yn + (size_t)N_ROWS * ROWB);               // 32 KB

    hipMemsetAsync(d_out, 0, sizeof(float), stream);
    norm_kernel<<<N_ROWS, 256, 0, stream>>>(X, Y, (unsigned short*)Xn, (unsigned short*)Yn, pos);
    const int ntiles = (N_ROWS / BM) * (N_ROWS / BN);   // 1024
    gemm_loss_kernel<<<dim3(ntiles), 512, 0, stream>>>(Xn, Yn, pos, out);
}

// Round 12
// 64.118 us; speedup vs baseline: 1.0718x; 1.0718x over previous
//
#include <hip/hip_runtime.h>
#include <hip/hip_bf16.h>

#define N_ROWS 8192
#define D_DIM  1024           // elements per row
#define ROWB   512            // fp4 row bytes (1024 elems * 0.5B)
#define DELTA  0.1f
#define EPSF   1e-8f

#define BM 256
#define BN 256
#define BKB 64                // K-tile row bytes = 128 fp4 elems = one k-step
#define NT (ROWB / BKB)       // 8 K-tiles

typedef __attribute__((ext_vector_type(4))) int   i32x4;
typedef __attribute__((ext_vector_type(8))) int   i32x8;
typedef __attribute__((ext_vector_type(4))) float f32x4;

// Software fp4 (e2m1) encode of v*32, RNE-by-midpoints, clamp at 6.
__device__ inline unsigned int fp4_enc(float v) {
    const unsigned int s = (__float_as_uint(v) >> 31) & 1u;
    float m = fminf(fabsf(v) * 32.0f, 6.0f);
    unsigned int c = 0;
    c += (m >= 0.25f); c += (m >= 0.75f); c += (m >= 1.25f); c += (m >= 1.75f);
    c += (m >= 2.5f);  c += (m >= 3.5f);  c += (m >= 5.0f);
    return (s << 3) | c;
}

// One block per row: compute xx, yy, xy; write normalized fp4 rows (x32) + fp32 pos.
// Block 0 also zeroes the output accumulator (replaces the memset dispatch;
// stream order guarantees it lands before the gemm kernel starts).
__global__ __launch_bounds__(256) void norm_kernel(
    const float* __restrict__ X, const float* __restrict__ Y,
    unsigned short* __restrict__ Xn, unsigned short* __restrict__ Yn,  // [8192][256] u16
    float* __restrict__ pos, float* __restrict__ out)
{
    const int row = blockIdx.x;
    const int t = threadIdx.x;            // 256 threads, 4 f32 each = 1024
    if (row == 0 && t == 0) out[0] = 0.0f;
    const float4 xv = reinterpret_cast<const float4*>(X + (size_t)row * D_DIM)[t];
    const float4 yv = reinterpret_cast<const float4*>(Y + (size_t)row * D_DIM)[t];

    float xx = xv.x*xv.x + xv.y*xv.y + xv.z*xv.z + xv.w*xv.w;
    float yy = yv.x*yv.x + yv.y*yv.y + yv.z*yv.z + yv.w*yv.w;
    float xy = xv.x*yv.x + xv.y*yv.y + xv.z*yv.z + xv.w*yv.w;

    #pragma unroll
    for (int off = 32; off > 0; off >>= 1) {
        xx += __shfl_xor(xx, off);
        yy += __shfl_xor(yy, off);
        xy += __shfl_xor(xy, off);
    }
    __shared__ float red[12];
    const int wid = t >> 6, lane = t & 63;
    if (lane == 0) { red[wid] = xx; red[4 + wid] = yy; red[8 + wid] = xy; }
    __syncthreads();
    xx = red[0] + red[1] + red[2] + red[3];
    yy = red[4] + red[5] + red[6] + red[7];
    xy = red[8] + red[9] + red[10] + red[11];

    const float rnx = 1.0f / fmaxf(sqrtf(xx), EPSF);
    const float rny = 1.0f / fmaxf(sqrtf(yy), EPSF);
    if (t == 0) pos[row] = xy * rnx * rny;

    // 4 fp4 nibbles -> one u16, K ascending low-to-high (identical for X and Y)
    const unsigned int px = fp4_enc(xv.x * rnx) | (fp4_enc(xv.y * rnx) << 4)
                          | (fp4_enc(xv.z * rnx) << 8) | (fp4_enc(xv.w * rnx) << 12);
    const unsigned int py = fp4_enc(yv.x * rny) | (fp4_enc(yv.y * rny) << 4)
                          | (fp4_enc(yv.z * rny) << 8) | (fp4_enc(yv.w * rny) << 12);
    Xn[(size_t)row * 256 + t] = (unsigned short)px;
    Yn[(size_t)row * 256 + t] = (unsigned short)py;
}

#define GLDS16(gptr, lptr) \
    __builtin_amdgcn_global_load_lds((const __attribute__((address_space(1))) void*)(gptr), \
                                     (__attribute__((address_space(3))) void*)(lptr), 16, 0, 0)

// Plain 16B LDS read into low half of an i32x8 (fp4 operand uses 4 regs).
__device__ inline i32x8 ld16(const unsigned char* p) {
    const i32x4 u = *reinterpret_cast<const i32x4*>(p);
    i32x8 r;
    r[0] = u[0]; r[1] = u[1]; r[2] = u[2]; r[3] = u[3];
    r[4] = 0; r[5] = 0; r[6] = 0; r[7] = 0;
    return r;
}

// ---- paired-row LDS layout (BKB=64) --------------------------------------
// LDS line l (128B) holds rows {2l, 2l+1}: logical chunk q = (h<<2)|kc
// (h = row&1, kc = 16B k-chunk 0..3) stored at physical chunk p = q^(l&7).
// Frag reads: 16 lanes sharing a k-chunk span 8 lines x 2 h -> every 16B slot
// hit exactly 2x = free 2-way alias (m136). Per-thread frag byte offset is
// row-block-independent; consecutive fragments step by exactly 1024B, so all
// reads are constant-offset derefs (ds_read_b128 offset immediates).
// Staging writes LDS linearly (gload_lds rule: base + lane*16); the swizzle
// is pre-applied to the GLOBAL source: for LDS (l = j*8 + lane>>3, c = lane&7)
// take q = c^(lane>>3) -> global row 2l+(q>>2), chunk q&3.
// --------------------------------------------------------------------------

// One 1KB staging unit (8 lines = 16 rows): per-thread one 16B gload_lds.
#define STAGE1(dst, gbase, kkb, j) { \
    const unsigned char* g_ = (gbase) + (size_t)((j) * 16 + srowoff) * ROWB + (kkb) + skc16; \
    GLDS16(g_, (dst) + (j) * 1024); }

// Stage one 256x64B panel (16 KB = 16 units): 2 units/thread (j = wv, 8+wv).
#define STAGE_P(dst, gbase, kkb) { \
    STAGE1(dst, gbase, kkb, wv); STAGE1(dst, gbase, kkb, 8 + wv); }

#define LOAD_A_G(g, pa) { _Pragma("unroll") for (int mi = 0; mi < 4; ++mi) \
    af[mi] = ld16((pa) + ((g) * 4 + mi) * 1024); }

#define LOAD_B_ALL(pb) { _Pragma("unroll") for (int nj = 0; nj < 4; ++nj) \
    bf[nj] = ld16((pb) + nj * 1024); }

// 16 mfma_scale; cbsz=4/blgp=4 = fp4 e2m1; unit scales (0x7F = e8m0 1.0)
#define MFMA_H(g) { _Pragma("unroll") for (int mi = 0; mi < 4; ++mi) { \
    _Pragma("unroll") for (int nj = 0; nj < 4; ++nj) { \
        acc[(g)*4+mi][nj] = __builtin_amdgcn_mfma_scale_f32_16x16x128_f8f6f4( \
            af[mi], bf[nj], acc[(g)*4+mi][nj], 4, 4, 0, 0x7F7F7F7F, 0, 0x7F7F7F7F); } } }

#define PRIO1() __builtin_amdgcn_s_setprio(1)
#define PRIO0() __builtin_amdgcn_s_setprio(0)

// epilogue inner loop; DIAG chosen at block level (diagonal only when row0==col0)
#define EPILOOP(DIAG) { \
    _Pragma("unroll") for (int mi = 0; mi < 8; ++mi) { \
        _Pragma("unroll") for (int jj = 0; jj < 4; ++jj) { \
            const int lr = wm * 128 + mi * 16 + (lane >> 4) * 4 + jj; \
            const float basev = DELTA - sPos[lr]; \
            _Pragma("unroll") for (int nj = 0; nj < 4; ++nj) { \
                float h = fmaxf(fmaf(acc[mi][nj][jj], inv, basev), 0.0f); \
                if (DIAG) { \
                    const int lc = wn * 64 + nj * 16 + (lane & 15); \
                    if (lr == lc) h = 0.0f; \
                } \
                if (nj & 1) l1 += h; else l0 += h; \
            } } } }

// S*1024 = (32Xn)*(32Yn)^T 256x256 fp4 tile; 3-buffer ring, BKB=64 (NT=8):
// ONE barrier + ONE counted vmcnt(4) per K-tile, NO mid-tile lgkm drain.
// Restage target buf[(kt+2)%3] was last read at tile kt-1; every wave past
// barrier kt has completed those reads (in-order DS + final-MFMA lgkm wait).
__global__ __launch_bounds__(512, 2) void gemm_loss_kernel(
    const unsigned char* __restrict__ A,   // Xn [N][512B] fp4
    const unsigned char* __restrict__ B,   // Yn [N][512B] fp4
    const float* __restrict__ pos,
    float* __restrict__ out)
{
    __shared__ __align__(16) unsigned char sA[3][BM * BKB];  // 48 KB
    __shared__ __align__(16) unsigned char sB[3][BN * BKB];  // 48 KB
    __shared__ float sPos[BM];
    __shared__ float redW[8];

    // XCD-aware swizzle (1024 blocks, 1024 % 8 == 0 -> bijective)
    const int nwg = gridDim.x;
    const int bid = blockIdx.x;
    const int cpx = nwg >> 3;
    const int swz = (bid & 7) * cpx + (bid >> 3);
    const int row0 = (swz >> 5) * BM;   // 32 tiles per dim
    const int col0 = (swz & 31) * BN;

    const int tid = threadIdx.x;
    const int lane = tid & 63;
    const int wv = tid >> 6;         // 8 waves: 2M x 4N
    const int wm = wv >> 2;          // rows [wm*128, +128)
    const int wn = wv & 3;           // cols [wn*64, +64)

    // staging per-lane constants (paired-row layout, see derivation above)
    const int sq = (lane & 7) ^ (lane >> 3);
    const int srowoff = 2 * (lane >> 3) + (sq >> 2);
    const int skc16 = (sq & 3) * 16;
    const unsigned char* Ab = A + (size_t)row0 * ROWB;
    const unsigned char* Bb = B + (size_t)col0 * ROWB;

    // per-thread invariant fragment-read byte offset within a panel
    const int fragbyte = ((lane >> 1) & 7) * 128
                       + (((((lane & 1) << 2) | (lane >> 4)) ^ ((lane >> 1) & 7)) * 16);
    const int aoff = wm * 8192 + fragbyte;
    const int boff = wn * 4096 + fragbyte;

    f32x4 acc[8][4] = {};
    i32x8 af[4], bf[4];

    // prologue: stage tiles 0 and 1 (8 stage loads/thread in flight)
    STAGE_P(&sA[0][0], Ab, 0);
    STAGE_P(&sB[0][0], Bb, 0);
    STAGE_P(&sA[1][0], Ab, BKB);
    STAGE_P(&sB[1][0], Bb, BKB);

    #pragma unroll
    for (int kt = 0; kt < NT; ++kt) {
        // boundary: tile kt's 4 loads (oldest) complete; kt+1's stay in flight
        if (kt == NT - 1) { asm volatile("s_waitcnt vmcnt(0)" ::: "memory"); }
        else              { asm volatile("s_waitcnt vmcnt(4)" ::: "memory"); }
        __builtin_amdgcn_s_barrier();
        __builtin_amdgcn_sched_barrier(0);

        const unsigned char* a = &sA[kt % 3][0];
        const unsigned char* b = &sB[kt % 3][0];
        const unsigned char* pa = a + aoff;
        const unsigned char* pb = b + boff;

        // frag-read issues first (critical path), then stage kt+2
        LOAD_B_ALL(pb);
        LOAD_A_G(0, pa);
        if (kt + 2 < NT) {
            STAGE_P(&sA[(kt + 2) % 3][0], Ab, (kt + 2) * BKB);
            STAGE_P(&sB[(kt + 2) % 3][0], Bb, (kt + 2) * BKB);
        }
        PRIO1(); MFMA_H(0); PRIO0();
        LOAD_A_G(1, pa);
        PRIO1(); MFMA_H(1); PRIO0();
    }

    // pos staged after the K-loop (keeps in-loop vmcnt accounting pure)
    if (tid < BM) sPos[tid] = pos[row0 + tid];
    __syncthreads();

    // epilogue: hinge = max(0, DELTA - pos[i] + S[i][j]); S = acc/1024 (x32 x32)
    const float inv = 1.0f / 1024.0f;
    float l0 = 0.0f, l1 = 0.0f;
    if (row0 == col0) { EPILOOP(1) } else { EPILOOP(0) }
    float local = l0 + l1;
    #pragma unroll
    for (int off = 32; off > 0; off >>= 1) local += __shfl_xor(local, off);
    if (lane == 0) redW[wv] = local;
    __syncthreads();
    if (tid == 0) {
        float s = 0.0f;
        #pragma unroll
        for (int w = 0; w < 8; ++w) s += redW[w];
        atomicAdd(out, s);
    }
}

extern "C" void kernel_launch(void* const* d_in, const int* in_sizes, int n_in,
                              void* d_out, int out_size, void* d_ws, size_t ws_size,
                              hipStream_t stream) {
    const float* X = (const float*)d_in[0];
    const float* Y = (const float*)d_in[1];
    float* out = (float*)d_out;

    unsigned char* Xn = (unsigned char*)d_ws;                        // 4 MB fp4
    unsigned char* Yn = Xn + (size_t)N_ROWS * ROWB;                  // 4 MB fp4
    float* pos = (float*)(Yn + (size_t)N_ROWS * ROWB);               // 32 KB

    norm_kernel<<<N_ROWS, 256, 0, stream>>>(X, Y, (unsigned short*)Xn, (unsigned short*)Yn, pos, out);
    const int ntiles = (N_ROWS / BM) * (N_ROWS / BN);   // 1024
    gemm_loss_kernel<<<dim3(ntiles), 512, 0, stream>>>(Xn, Yn, pos, out);
}